// Round 1
// baseline (1479.088 us; speedup 1.0000x reference)
//
#include <hip/hip_runtime.h>
#include <cstdint>

#define N_NODES 8192
#define D_OSC   64
#define E_EDGE  1048576   // both E_K and E_HK

__device__ __forceinline__ float waveReduceSum(float v) {
#pragma unroll
  for (int off = 32; off > 0; off >>= 1)
    v += __shfl_xor(v, off, 64);
  return v;
}

// g = tanh(state_H); zero the accumulators / counters we rely on (ws is poisoned 0xAA)
__global__ void k_prep_scalar(const float* __restrict__ sH, float* g, float* y1,
                              float* y2, int* cnt) {
  int i = blockIdx.x * blockDim.x + threadIdx.x;
  if (i < N_NODES) {
    g[i] = tanhf(sH[i]);
    y1[i] = 0.f;
    y2[i] = 0.f;
    cnt[i] = 0;
  }
}

// row-normalize state_K -> sK ; one wave per node, lane = dim
__global__ void k_normalize(const float* __restrict__ stateK, float* __restrict__ sK) {
  int node = blockIdx.x * (blockDim.x >> 6) + (threadIdx.x >> 6);
  int lane = threadIdx.x & 63;
  float v = stateK[node * D_OSC + lane];
  float ss = waveReduceSum(v * v);
  sK[node * D_OSC + lane] = v / sqrtf(ss);
}

// incidence counts per node (both edge sets)
__global__ void k_count(const int2* __restrict__ indK, const int2* __restrict__ indHK,
                        int* cnt) {
  int stride = gridDim.x * blockDim.x;
  for (int idx = blockIdx.x * blockDim.x + threadIdx.x; idx < 2 * E_EDGE; idx += stride) {
    int2 pr = (idx < E_EDGE) ? indK[idx] : indHK[idx - E_EDGE];
    atomicAdd(&cnt[pr.x], 1);
    atomicAdd(&cnt[pr.y], 1);
  }
}

// exclusive scan of 8192 counts -> offs[8193], plus cursor copy. Single block.
__global__ void k_scan(const int* __restrict__ cnt, int* offs, int* curs) {
  __shared__ int lds[256];
  int t = threadIdx.x;
  int local[32];
  int s = 0;
#pragma unroll
  for (int k = 0; k < 32; ++k) { local[k] = cnt[t * 32 + k]; s += local[k]; }
  lds[t] = s;
  __syncthreads();
  for (int off = 1; off < 256; off <<= 1) {
    int v = (t >= off) ? lds[t - off] : 0;
    __syncthreads();
    lds[t] += v;
    __syncthreads();
  }
  int run = lds[t] - s;  // exclusive prefix
#pragma unroll
  for (int k = 0; k < 32; ++k) {
    offs[t * 32 + k] = run;
    curs[t * 32 + k] = run;
    run += local[k];
  }
  if (t == 255) offs[N_NODES] = run;
}

// scatter incidence records: enc = edge_id | endpoint<<20 | set<<21
__global__ void k_fill(const int2* __restrict__ indK, const int2* __restrict__ indHK,
                       int* curs, unsigned* __restrict__ inc) {
  int stride = gridDim.x * blockDim.x;
  for (int idx = blockIdx.x * blockDim.x + threadIdx.x; idx < 2 * E_EDGE; idx += stride) {
    int set = idx >= E_EDGE;
    int e = set ? idx - E_EDGE : idx;
    int2 pr = set ? indHK[e] : indK[e];
    unsigned tag = (unsigned)e | ((unsigned)set << 21);
    int p0 = atomicAdd(&curs[pr.x], 1);
    inc[p0] = tag;                  // endpoint 0
    int p1 = atomicAdd(&curs[pr.y], 1);
    inc[p1] = tag | (1u << 20);     // endpoint 1
  }
}

// per-edge coefficients: one wave per edge, 64-dim dot via shuffle reduce
__global__ void k_edge_coeff(const float* __restrict__ sK, const int2* __restrict__ indK,
                             const int2* __restrict__ indHK, const float* __restrict__ wK,
                             const float* __restrict__ wHK, const float* __restrict__ g,
                             const float* __restrict__ kH, const float* __restrict__ kK,
                             float* cK, float* cH, float* cKc) {
  int lane = threadIdx.x & 63;
  int wid = (blockIdx.x * blockDim.x + threadIdx.x) >> 6;
  int nw = (gridDim.x * blockDim.x) >> 6;
  float rKH = 1.f / kH[0];
  float rKK = 1.f / kK[0];
  for (int w = wid; w < 2 * E_EDGE; w += nw) {
    int set = w >= E_EDGE;
    int e = set ? w - E_EDGE : w;
    int2 pr = set ? indHK[e] : indK[e];
    float a = sK[pr.x * D_OSC + lane];
    float b = sK[pr.y * D_OSC + lane];
    float s = waveReduceSum(a * b);
    if (lane == 0) {
      if (set) {
        float ww = wHK[e];
        cH[e] = s * ww * rKH;                    // Gram * w_hk / kappa_H
        cKc[e] = -g[pr.x] * g[pr.y] * ww * rKK;  // -g0*g1*w_hk / kappa_K
      } else {
        cK[e] = wK[e] * s;                       // w_K * s
      }
    }
  }
}

// one streaming pass over W: y1 = W@g (block-owned rows, plain reduce+atomic across
// 4 col-blocks), y2 = W^T@g (per-thread column partials in registers, 1 atomic/col/block)
#define MV_ROWS 32
#define MV_CB   2048
__global__ __launch_bounds__(256) void k_matvec(const float* __restrict__ W,
                                                const float* __restrict__ g,
                                                float* y1, float* y2) {
  int t = threadIdx.x;
  int r0 = blockIdx.x * MV_ROWS;
  int c0 = blockIdx.y * MV_CB;
  int wid = t >> 6, lane = t & 63;
  float gcol[8], y2p[8];
#pragma unroll
  for (int k = 0; k < 8; ++k) { gcol[k] = g[c0 + t + 256 * k]; y2p[k] = 0.f; }
  __shared__ float red[MV_ROWS][4];
  for (int r = 0; r < MV_ROWS; ++r) {
    int i = r0 + r;
    float gi = g[i];
    const float* row = W + (size_t)i * N_NODES + c0 + t;
    float acc = 0.f;
#pragma unroll
    for (int k = 0; k < 8; ++k) {
      float w = row[256 * k];
      acc = fmaf(w, gcol[k], acc);
      y2p[k] = fmaf(w, gi, y2p[k]);
    }
    acc = waveReduceSum(acc);
    if (lane == 0) red[r][wid] = acc;
  }
  __syncthreads();
  if (t < MV_ROWS)
    atomicAdd(&y1[r0 + t], red[t][0] + red[t][1] + red[t][2] + red[t][3]);
#pragma unroll
  for (int k = 0; k < 8; ++k) atomicAdd(&y2[c0 + t + 256 * k], y2p[k]);
}

// gather: one wave per node, lane = dim. Zero float atomics.
__global__ void k_gather(const float* __restrict__ sK, const int* __restrict__ offs,
                         const unsigned* __restrict__ inc, const int2* __restrict__ indK,
                         const int2* __restrict__ indHK, const float* __restrict__ cK,
                         const float* __restrict__ cH, const float* __restrict__ cKc,
                         const float* __restrict__ g, const float* __restrict__ y1,
                         const float* __restrict__ y2, const float* __restrict__ sH,
                         const float* __restrict__ bias, float* __restrict__ out) {
  int node = blockIdx.x * (blockDim.x >> 6) + (threadIdx.x >> 6);
  int lane = threadIdx.x & 63;
  float skl = sK[node * D_OSC + lane];
  int beg = offs[node], end = offs[node + 1];
  float acc = 0.f, accH = 0.f;
  int p = beg;
  for (; p + 4 <= end; p += 4) {
    int oth[4];
    float cf[4];
#pragma unroll
    for (int j = 0; j < 4; ++j) {
      unsigned enc = (unsigned)__builtin_amdgcn_readfirstlane((int)inc[p + j]);
      int e = enc & 0xFFFFFu;
      int ep = (enc >> 20) & 1;
      if (enc >> 21) {
        int2 pr = indHK[e];
        oth[j] = ep ? pr.x : pr.y;
        cf[j] = cKc[e];
        accH += cH[e] * g[oth[j]];
      } else {
        int2 pr = indK[e];
        oth[j] = ep ? pr.x : pr.y;
        cf[j] = cK[e];
      }
    }
#pragma unroll
    for (int j = 0; j < 4; ++j)
      acc = fmaf(cf[j], sK[oth[j] * D_OSC + lane], acc);
  }
  for (; p < end; ++p) {
    unsigned enc = (unsigned)__builtin_amdgcn_readfirstlane((int)inc[p]);
    int e = enc & 0xFFFFFu;
    int ep = (enc >> 20) & 1;
    int oth;
    float cf;
    if (enc >> 21) {
      int2 pr = indHK[e];
      oth = ep ? pr.x : pr.y;
      cf = cKc[e];
      accH += cH[e] * g[oth];
    } else {
      int2 pr = indK[e];
      oth = ep ? pr.x : pr.y;
      cf = cK[e];
    }
    acc = fmaf(cf, sK[oth * D_OSC + lane], acc);
  }
  // f_K = -acc + sK * (sK . acc)
  float dot = waveReduceSum(skl * acc);
  out[N_NODES + node * D_OSC + lane] = fmaf(skl, dot, -acc);
  if (lane == 0)
    out[node] = accH + 0.5f * (y1[node] + y2[node]) - sH[node] + bias[node];
}

extern "C" void kernel_launch(void* const* d_in, const int* in_sizes, int n_in,
                              void* d_out, int out_size, void* d_ws, size_t ws_size,
                              hipStream_t stream) {
  const float* state_H    = (const float*)d_in[0];
  const float* state_K    = (const float*)d_in[1];
  const int2*  ind_K      = (const int2*)d_in[2];
  const int2*  ind_HK     = (const int2*)d_in[3];
  const float* kappa_K    = (const float*)d_in[4];
  const float* kappa_H    = (const float*)d_in[5];
  const float* weights_H  = (const float*)d_in[6];
  const float* bias_H     = (const float*)d_in[7];
  const float* weights_HK = (const float*)d_in[8];
  const float* w_K        = (const float*)d_in[9];
  float* out = (float*)d_out;

  char* w = (char*)d_ws;
  float* sK   = (float*)w; w += (size_t)N_NODES * D_OSC * 4;
  float* g    = (float*)w; w += (size_t)N_NODES * 4;
  float* y1   = (float*)w; w += (size_t)N_NODES * 4;
  float* y2   = (float*)w; w += (size_t)N_NODES * 4;
  int*   cnt  = (int*)w;   w += (size_t)N_NODES * 4;
  int*   offs = (int*)w;   w += (size_t)(N_NODES + 16) * 4;
  int*   curs = (int*)w;   w += (size_t)N_NODES * 4;
  float* cK   = (float*)w; w += (size_t)E_EDGE * 4;
  float* cH   = (float*)w; w += (size_t)E_EDGE * 4;
  float* cKc  = (float*)w; w += (size_t)E_EDGE * 4;
  unsigned* inc = (unsigned*)w;

  k_prep_scalar<<<N_NODES / 256, 256, 0, stream>>>(state_H, g, y1, y2, cnt);
  k_normalize<<<N_NODES / 4, 256, 0, stream>>>(state_K, sK);
  k_count<<<2048, 256, 0, stream>>>(ind_K, ind_HK, cnt);
  k_scan<<<1, 256, 0, stream>>>(cnt, offs, curs);
  k_fill<<<2048, 256, 0, stream>>>(ind_K, ind_HK, curs, inc);
  k_edge_coeff<<<4096, 256, 0, stream>>>(sK, ind_K, ind_HK, w_K, weights_HK, g,
                                         kappa_H, kappa_K, cK, cH, cKc);
  k_matvec<<<dim3(N_NODES / MV_ROWS, N_NODES / MV_CB), 256, 0, stream>>>(weights_H, g,
                                                                         y1, y2);
  k_gather<<<N_NODES / 4, 256, 0, stream>>>(sK, offs, inc, ind_K, ind_HK, cK, cH, cKc,
                                            g, y1, y2, state_H, bias_H, out);
}

// Round 2
// 840.825 us; speedup vs baseline: 1.7591x; 1.7591x over previous
//
#include <hip/hip_runtime.h>
#include <cstdint>

#define N_NODES 8192
#define D_OSC   64
#define E_EDGE  1048576   // both E_K and E_HK

__device__ __forceinline__ float waveReduceSum(float v) {
#pragma unroll
  for (int off = 32; off > 0; off >>= 1)
    v += __shfl_xor(v, off, 64);
  return v;
}

// g = tanh(state_H); zero the accumulators / counters (ws is poisoned 0xAA)
__global__ void k_prep_scalar(const float* __restrict__ sH, float* g, float* y1,
                              float* y2, int* cnt) {
  int i = blockIdx.x * blockDim.x + threadIdx.x;
  if (i < N_NODES) {
    g[i] = tanhf(sH[i]);
    y1[i] = 0.f;
    y2[i] = 0.f;
    cnt[i] = 0;
  }
}

// row-normalize state_K -> sK ; one wave per node, lane = dim
__global__ void k_normalize(const float* __restrict__ stateK, float* __restrict__ sK) {
  int node = blockIdx.x * (blockDim.x >> 6) + (threadIdx.x >> 6);
  int lane = threadIdx.x & 63;
  float v = stateK[node * D_OSC + lane];
  float ss = waveReduceSum(v * v);
  sK[node * D_OSC + lane] = v / sqrtf(ss);
}

// incidence counts per node (both edge sets)
__global__ void k_count(const int2* __restrict__ indK, const int2* __restrict__ indHK,
                        int* cnt) {
  int stride = gridDim.x * blockDim.x;
  for (int idx = blockIdx.x * blockDim.x + threadIdx.x; idx < 2 * E_EDGE; idx += stride) {
    int2 pr = (idx < E_EDGE) ? indK[idx] : indHK[idx - E_EDGE];
    atomicAdd(&cnt[pr.x], 1);
    atomicAdd(&cnt[pr.y], 1);
  }
}

// exclusive scan of 8192 counts -> offs[8193], plus cursor copy. Single block.
__global__ void k_scan(const int* __restrict__ cnt, int* offs, int* curs) {
  __shared__ int lds[256];
  int t = threadIdx.x;
  int local[32];
  int s = 0;
#pragma unroll
  for (int k = 0; k < 32; ++k) { local[k] = cnt[t * 32 + k]; s += local[k]; }
  lds[t] = s;
  __syncthreads();
  for (int off = 1; off < 256; off <<= 1) {
    int v = (t >= off) ? lds[t - off] : 0;
    __syncthreads();
    lds[t] += v;
    __syncthreads();
  }
  int run = lds[t] - s;  // exclusive prefix
#pragma unroll
  for (int k = 0; k < 32; ++k) {
    offs[t * 32 + k] = run;
    curs[t * 32 + k] = run;
    run += local[k];
  }
  if (t == 255) offs[N_NODES] = run;
}

// Fused coeff + fill. 16-lane group per edge (4 edges/wave), float4 row loads.
// Writes self-contained 16B records: {other_node, cf, h_contrib, pad}.
//   K edge:  cf = w_K[e] * s                      h = 0
//   HK edge: cf = -g0*g1*w_hk/kappa_K             h = (s*w_hk/kappa_H) * g[other]
__global__ void k_coeff_fill(const float* __restrict__ sK, const int2* __restrict__ indK,
                             const int2* __restrict__ indHK, const float* __restrict__ wK,
                             const float* __restrict__ wHK, const float* __restrict__ g,
                             const float* __restrict__ kH, const float* __restrict__ kK,
                             int* curs, int4* __restrict__ recs) {
  int lane = threadIdx.x & 63;
  int grp = lane >> 4;   // 0..3
  int l16 = lane & 15;
  int wid = (blockIdx.x * blockDim.x + threadIdx.x) >> 6;
  int nw = (gridDim.x * blockDim.x) >> 6;
  float rKH = 1.f / kH[0];
  float rKK = 1.f / kK[0];
  const float4* sK4 = (const float4*)sK;
  for (int base = wid * 4; base < 2 * E_EDGE; base += nw * 4) {
    int w = base + grp;
    int set = w >= E_EDGE;
    int e = set ? w - E_EDGE : w;
    int2 pr = set ? indHK[e] : indK[e];
    float4 a = sK4[pr.x * 16 + l16];
    float4 b = sK4[pr.y * 16 + l16];
    float d = a.x * b.x + a.y * b.y + a.z * b.z + a.w * b.w;
#pragma unroll
    for (int off = 8; off > 0; off >>= 1) d += __shfl_xor(d, off, 64);
    if (l16 == 0) {
      float cf, hx, hy;
      if (set) {
        float ww = wHK[e];
        float ch = d * ww * rKH;
        float gx = g[pr.x], gy = g[pr.y];
        cf = -gx * gy * ww * rKK;
        hx = ch * gy;   // record stored at node x: pairs with g[y]
        hy = ch * gx;
      } else {
        cf = wK[e] * d;
        hx = 0.f;
        hy = 0.f;
      }
      int p0 = atomicAdd(&curs[pr.x], 1);
      recs[p0] = make_int4(pr.y, __float_as_int(cf), __float_as_int(hx), 0);
      int p1 = atomicAdd(&curs[pr.y], 1);
      recs[p1] = make_int4(pr.x, __float_as_int(cf), __float_as_int(hy), 0);
    }
  }
}

// one streaming pass over W: y1 = W@g, y2 = W^T@g
#define MV_ROWS 32
#define MV_CB   2048
__global__ __launch_bounds__(256) void k_matvec(const float* __restrict__ W,
                                                const float* __restrict__ g,
                                                float* y1, float* y2) {
  int t = threadIdx.x;
  int r0 = blockIdx.x * MV_ROWS;
  int c0 = blockIdx.y * MV_CB;
  int wid = t >> 6, lane = t & 63;
  float gcol[8], y2p[8];
#pragma unroll
  for (int k = 0; k < 8; ++k) { gcol[k] = g[c0 + t + 256 * k]; y2p[k] = 0.f; }
  __shared__ float red[MV_ROWS][4];
  for (int r = 0; r < MV_ROWS; ++r) {
    int i = r0 + r;
    float gi = g[i];
    const float* row = W + (size_t)i * N_NODES + c0 + t;
    float acc = 0.f;
#pragma unroll
    for (int k = 0; k < 8; ++k) {
      float w = row[256 * k];
      acc = fmaf(w, gcol[k], acc);
      y2p[k] = fmaf(w, gi, y2p[k]);
    }
    acc = waveReduceSum(acc);
    if (lane == 0) red[r][wid] = acc;
  }
  __syncthreads();
  if (t < MV_ROWS)
    atomicAdd(&y1[r0 + t], red[t][0] + red[t][1] + red[t][2] + red[t][3]);
#pragma unroll
  for (int k = 0; k < 8; ++k) atomicAdd(&y2[c0 + t + 256 * k], y2p[k]);
}

// gather: one wave per node, lane = dim. Streams self-contained records.
__global__ void k_gather(const float* __restrict__ sK, const int* __restrict__ offs,
                         const int4* __restrict__ recs, const float* __restrict__ y1,
                         const float* __restrict__ y2, const float* __restrict__ sH,
                         const float* __restrict__ bias, float* __restrict__ out) {
  int node = blockIdx.x * (blockDim.x >> 6) + (threadIdx.x >> 6);
  int lane = threadIdx.x & 63;
  float skl = sK[node * D_OSC + lane];
  int beg = __builtin_amdgcn_readfirstlane(offs[node]);
  int end = __builtin_amdgcn_readfirstlane(offs[node + 1]);
  float acc = 0.f, accH = 0.f;
  int p = beg;
  for (; p + 8 <= end; p += 8) {
    int4 r[8];
#pragma unroll
    for (int j = 0; j < 8; ++j) r[j] = recs[p + j];
    float v[8];
#pragma unroll
    for (int j = 0; j < 8; ++j) v[j] = sK[r[j].x * D_OSC + lane];
#pragma unroll
    for (int j = 0; j < 8; ++j) {
      acc = fmaf(__int_as_float(r[j].y), v[j], acc);
      accH += __int_as_float(r[j].z);
    }
  }
  for (; p < end; ++p) {
    int4 r0 = recs[p];
    acc = fmaf(__int_as_float(r0.y), sK[r0.x * D_OSC + lane], acc);
    accH += __int_as_float(r0.z);
  }
  // f_K = -acc + sK * (sK . acc)
  float dot = waveReduceSum(skl * acc);
  out[N_NODES + node * D_OSC + lane] = fmaf(skl, dot, -acc);
  if (lane == 0)
    out[node] = accH + 0.5f * (y1[node] + y2[node]) - sH[node] + bias[node];
}

extern "C" void kernel_launch(void* const* d_in, const int* in_sizes, int n_in,
                              void* d_out, int out_size, void* d_ws, size_t ws_size,
                              hipStream_t stream) {
  const float* state_H    = (const float*)d_in[0];
  const float* state_K    = (const float*)d_in[1];
  const int2*  ind_K      = (const int2*)d_in[2];
  const int2*  ind_HK     = (const int2*)d_in[3];
  const float* kappa_K    = (const float*)d_in[4];
  const float* kappa_H    = (const float*)d_in[5];
  const float* weights_H  = (const float*)d_in[6];
  const float* bias_H     = (const float*)d_in[7];
  const float* weights_HK = (const float*)d_in[8];
  const float* w_K        = (const float*)d_in[9];
  float* out = (float*)d_out;

  char* w = (char*)d_ws;
  float* sK   = (float*)w; w += (size_t)N_NODES * D_OSC * 4;          // 2 MB
  float* g    = (float*)w; w += (size_t)N_NODES * 4;
  float* y1   = (float*)w; w += (size_t)N_NODES * 4;
  float* y2   = (float*)w; w += (size_t)N_NODES * 4;
  int*   cnt  = (int*)w;   w += (size_t)N_NODES * 4;
  int*   offs = (int*)w;   w += (size_t)(N_NODES + 16) * 4;
  int*   curs = (int*)w;   w += (size_t)N_NODES * 4;
  int4*  recs = (int4*)w;  // 4*E_EDGE records * 16B = 67 MB

  k_prep_scalar<<<N_NODES / 256, 256, 0, stream>>>(state_H, g, y1, y2, cnt);
  k_normalize<<<N_NODES / 4, 256, 0, stream>>>(state_K, sK);
  k_count<<<2048, 256, 0, stream>>>(ind_K, ind_HK, cnt);
  k_scan<<<1, 256, 0, stream>>>(cnt, offs, curs);
  k_coeff_fill<<<4096, 256, 0, stream>>>(sK, ind_K, ind_HK, w_K, weights_HK, g,
                                         kappa_H, kappa_K, curs, recs);
  k_matvec<<<dim3(N_NODES / MV_ROWS, N_NODES / MV_CB), 256, 0, stream>>>(weights_H, g,
                                                                         y1, y2);
  k_gather<<<N_NODES / 4, 256, 0, stream>>>(sK, offs, recs, y1, y2, state_H, bias_H,
                                            out);
}